// Round 1
// baseline (417.610 us; speedup 1.0000x reference)
//
#include <hip/hip_runtime.h>

#define NPTS  32768
#define DIM   256
#define KCB   1024

#define ZQ_OFF   0
#define LOSS_OFF 8388608
#define IDX_OFF  8388609

typedef __attribute__((ext_vector_type(8))) short short8;
typedef __attribute__((ext_vector_type(4))) float f32x4;
typedef unsigned short ushort_t;
typedef unsigned int u32;

// z layout [B, D, H, W]: point n = b*1024 + h*32 + w ; elem (n,d) at b*262144 + d*1024 + hw
__device__ __forceinline__ int z_base(int n) { return ((n >> 10) << 18) | (n & 1023); }

// RNE float->bf16 (bits)
__device__ __forceinline__ ushort_t f2bf(float f) {
    u32 u = __float_as_uint(f);
    u += 0x7FFFu + ((u >> 16) & 1u);
    return (ushort_t)(u >> 16);
}

__device__ __forceinline__ unsigned long long pack_vi(float v, int i) {
    u32 u = __float_as_uint(v);
    u32 key = (u & 0x80000000u) ? ~u : u;   // monotone float->uint (finite)
    return ((unsigned long long)key << 32) | (u32)i;
}

// ---- numpy pairwise sum (AVX512 npyv order) of squares, 128 elems ----
__device__ __forceinline__ float np_half_sq(const float* __restrict__ p, int stride) {
    float S[16];
#pragma unroll
    for (int l = 0; l < 16; ++l) {
        float t[8];
#pragma unroll
        for (int j = 0; j < 8; ++j) {
            float v = p[(j * 16 + l) * stride];
            t[j] = __fmul_rn(v, v);
        }
        S[l] = __fadd_rn(__fadd_rn(__fadd_rn(t[0], t[1]), __fadd_rn(t[2], t[3])),
                         __fadd_rn(__fadd_rn(t[4], t[5]), __fadd_rn(t[6], t[7])));
    }
    float u[8];
#pragma unroll
    for (int i = 0; i < 8; ++i) u[i] = __fadd_rn(S[i], S[i + 8]);
    float v4[4];
#pragma unroll
    for (int i = 0; i < 4; ++i) v4[i] = __fadd_rn(u[i], u[i + 4]);
    return __fadd_rn(__fadd_rn(v4[0], v4[2]), __fadd_rn(v4[1], v4[3]));
}
__device__ __forceinline__ float np_sum256_sq(const float* __restrict__ p, int stride) {
    return __fadd_rn(np_half_sq(p, stride), np_half_sq(p + 128 * stride, stride));
}

// same square chain (bit-identical z2), abs-sum fused into the same pass (order-free bound input)
__device__ __forceinline__ float np_half_sq_abs(const float* __restrict__ p, int stride, float* aacc) {
    float S[16]; float a = *aacc;
#pragma unroll
    for (int l = 0; l < 16; ++l) {
        float t[8];
#pragma unroll
        for (int j = 0; j < 8; ++j) {
            float v = p[(j * 16 + l) * stride];
            t[j] = __fmul_rn(v, v);
            a = __fadd_rn(a, fabsf(v));
        }
        S[l] = __fadd_rn(__fadd_rn(__fadd_rn(t[0], t[1]), __fadd_rn(t[2], t[3])),
                         __fadd_rn(__fadd_rn(t[4], t[5]), __fadd_rn(t[6], t[7])));
    }
    float u[8];
#pragma unroll
    for (int i = 0; i < 8; ++i) u[i] = __fadd_rn(S[i], S[i + 8]);
    float v4[4];
#pragma unroll
    for (int i = 0; i < 4; ++i) v4[i] = __fadd_rn(u[i], u[i + 4]);
    *aacc = a;
    return __fadd_rn(__fadd_rn(v4[0], v4[2]), __fadd_rn(v4[1], v4[3]));
}

// blocks 0..127: per-point z2 (np order) + fused abs-sum -> eps (single z pass).
// blocks 128..131: e2/e2h + swizzled chunked bf16 image of emb for global_load_lds:
//   chunk (kc,dt) = 4KB covering k in [kc*64,+64), d in [dt*32,+32).
//   within chunk, 16B slot s (0..255): row=s>>2, sl=s&3, lq=sl^((row>>1)&3),
//   holds bf16 emb[kc*64+row][dt*32 + lq*8 .. +7]  (XOR bank swizzle baked in).
__global__ __launch_bounds__(256) void setup_kernel(
    const float* __restrict__ z, const float* __restrict__ emb,
    float* __restrict__ z2, float* __restrict__ eps,
    float* __restrict__ e2, float* __restrict__ e2h,
    ushort_t* __restrict__ ebf,
    double* __restrict__ loss_acc, unsigned int* __restrict__ ticket)
{
    if (blockIdx.x < 128) {
        int n = blockIdx.x * 256 + threadIdx.x;
        const float* p = z + z_base(n);
        float a = 0.0f;
        float h0 = np_half_sq_abs(p, 1024, &a);
        float h1 = np_half_sq_abs(p + 128 * 1024, 1024, &a);
        z2[n] = __fadd_rn(h0, h1);
        eps[n] = __builtin_fmaf(1e-5f, a, 3e-4f);   // sound |d~ - d| bound
        if (blockIdx.x == 0 && threadIdx.x == 0) { *loss_acc = 0.0; *ticket = 0u; }
    } else {
        int kb = (blockIdx.x - 128) * 256;
        for (int i = threadIdx.x; i < 8192; i += 256) {
            int c = i >> 8, s = i & 255;
            int kcl = c >> 3, dtc = c & 7;
            int row = s >> 2, sl = s & 3;
            int lq = sl ^ ((row >> 1) & 3);
            int k = kb + (kcl << 6) + row;
            int d0 = dtc * 32 + lq * 8;
            const float* e = emb + k * 256 + d0;
            short8 ov;
#pragma unroll
            for (int j = 0; j < 8; ++j) ov[j] = (short)f2bf(e[j]);
            *(short8*)(ebf + ((((kb >> 6) + kcl) << 3) + dtc) * 2048 + (s << 3)) = ov;
        }
        int k = kb + threadIdx.x;
        float s = np_sum256_sq(emb + k * DIM, 1);
        e2[k] = s;
        e2h[k] = 0.5f * s;
    }
}

// ---------------- MFMA distance + candidate filter + exact recheck ----------------
// block: 64 points x 1024 k. 4 waves; each wave owns a 256-k quarter (barrier-free main loop).
// A-fragments (z) hoisted to 128 VGPRs once; acc init = -e2/2; es chunks 64k x 32d (4KB)
// staged per-wave via global_load_lds, 3-buffer pipeline, counted vmcnt (never 0 mid-loop).
#define ZS_STRIDE 264

__device__ __forceinline__ void async_cp16(const ushort_t* g, ushort_t* l) {
    __builtin_amdgcn_global_load_lds(
        (const __attribute__((address_space(1))) u32*)g,
        (__attribute__((address_space(3))) u32*)l, 16, 0, 0);
}

#define WAITVM8 asm volatile("s_waitcnt vmcnt(8)" ::: "memory")
#define WAITVM4 asm volatile("s_waitcnt vmcnt(4)" ::: "memory")
#define WAITVM0 asm volatile("s_waitcnt vmcnt(0)" ::: "memory")
#define WAITLG0 asm volatile("s_waitcnt lgkmcnt(0)" ::: "memory")
#define MEMBAR  asm volatile("" ::: "memory")

__global__ __launch_bounds__(256, 2) void dist_kernel(
    const float* __restrict__ z, const float* __restrict__ emb,
    const ushort_t* __restrict__ ebf,
    const float* __restrict__ z2w, const float* __restrict__ e2w,
    const float* __restrict__ e2hw, const float* __restrict__ epsw,
    float* __restrict__ out_idx)
{
    // uni: zs (64x264 bf16, transient) UNION es (4 waves x 3 bufs x 4KB) UNION zx (32x68 f32)
    __shared__ __align__(16) short uni[24576];          // 49152 B
    __shared__ float e2hS[1024];
    __shared__ float maxred[256];
    __shared__ float thrS[64], epsS[64], z2S[64];
    __shared__ unsigned int cntS[64];
    __shared__ unsigned long long bestS[64];
    __shared__ int cl[64 * 32];
    __shared__ int ovfS;

    const int tid = threadIdx.x;
    const int w  = tid >> 6;       // wave 0..3
    const int l  = tid & 63;
    const int lq = l >> 4;
    const int lr = l & 15;
    const int sw8 = ((lq ^ ((lr >> 1) & 3)) << 3);   // swizzled slot (short offset)
    const int n0 = blockIdx.x << 6;
    const int zb = z_base(n0);
    const int wq = w << 8;                            // wave k base (0,256,512,768)
    const int wbase = w * 6144;                       // shorts: 3 bufs x 2048

    if (tid < 64) {
        cntS[tid] = 0u; bestS[tid] = 0x7FFFFFFFFFFFFFFFULL;
        epsS[tid] = epsw[n0 + tid]; z2S[tid] = z2w[n0 + tid];
    }
    if (tid == 0) ovfS = 0;
    for (int i = tid; i < 64 * 32; i += 256) cl[i] = 0;
    for (int i = tid; i < 1024; i += 256) e2hS[i] = e2hw[i];

    // stage zs (fp32 -> bf16, transpose to [pt][d])
    {
        short* zs = uni;
        int q = tid & 15, d0 = tid >> 4;
#pragma unroll 4
        for (int i = 0; i < 16; ++i) {
            int d = d0 + 16 * i;
            float4 v = *(const float4*)(z + zb + (d << 10) + 4 * q);
            zs[(4 * q + 0) * ZS_STRIDE + d] = (short)f2bf(v.x);
            zs[(4 * q + 1) * ZS_STRIDE + d] = (short)f2bf(v.y);
            zs[(4 * q + 2) * ZS_STRIDE + d] = (short)f2bf(v.z);
            zs[(4 * q + 3) * ZS_STRIDE + d] = (short)f2bf(v.w);
        }
    }
    __syncthreads();

    // hoist A-fragments (one time; zs is dead afterwards)
    short8 af[4][8];
    {
        const short* zs = uni;
#pragma unroll
        for (int mt = 0; mt < 4; ++mt)
#pragma unroll
            for (int d8 = 0; d8 < 8; ++d8)
                af[mt][d8] = *(const short8*)(zs + (16 * mt + lr) * ZS_STRIDE + d8 * 32 + lq * 8);
    }

    f32x4 acc[4][4];
#pragma unroll
    for (int nt = 0; nt < 4; ++nt) {
        float e = e2hS[wq + 16 * nt + lr];
        f32x4 iv = { -e, -e, -e, -e };
#pragma unroll
        for (int mt = 0; mt < 4; ++mt) acc[mt][nt] = iv;
    }
    __syncthreads();   // all af reads done before es overwrites zs region

    // prologue: issue chunks 0,1,2 of this wave's kt0
    {
        const int kc0 = (w << 2);
#pragma unroll
        for (int c = 0; c < 3; ++c) {
            const ushort_t* gs = ebf + (((kc0 << 3) + c) * 2048) + (l << 3);
            ushort_t* ld = (ushort_t*)(uni + wbase + c * 2048);
            async_cp16(gs,        ld);
            async_cp16(gs +  512, ld +  512);
            async_cp16(gs + 1024, ld + 1024);
            async_cp16(gs + 1536, ld + 1536);
        }
    }
    WAITVM8;   // chunk 0 landed
    short8 c0, c1, c2, c3;
    {
        const short* esb = uni + wbase;
        c0 = *(const short8*)(esb + ( 0 + lr) * 32 + sw8);
        c1 = *(const short8*)(esb + (16 + lr) * 32 + sw8);
        c2 = *(const short8*)(esb + (32 + lr) * 32 + sw8);
        c3 = *(const short8*)(esb + (48 + lr) * 32 + sw8);
    }

    int bufr = 0;   // buffer of the CURRENT chunk (g % 3)
#pragma unroll 1
    for (int kt = 0; kt < 5; ++kt) {            // kt4 = redo of kt0 with final threshold
        const bool kt4 = (kt == 4);
        const int ktr = kt4 ? 0 : kt;
        const int kb = wq + (ktr << 6);
#pragma unroll
        for (int dt = 0; dt < 8; ++dt) {
            const int bufr1 = (bufr == 2) ? 0 : bufr + 1;
            WAITLG0;   // current-buffer frag reads (issued last iter) are consumed
            if (!kt4 || dt < 5) {               // issue chunk g+3 into current buffer
                const int dtn = (dt + 3) & 7;
                const int ktn = (dt >= 5) ? kt + 1 : kt;
                const int kcn = (w << 2) + ((ktn < 4) ? ktn : 0);
                const ushort_t* gs = ebf + (((kcn << 3) + dtn) * 2048) + (l << 3);
                ushort_t* ld = (ushort_t*)(uni + wbase + bufr * 2048);
                async_cp16(gs,        ld);
                async_cp16(gs +  512, ld +  512);
                async_cp16(gs + 1024, ld + 1024);
                async_cp16(gs + 1536, ld + 1536);
            }
            if (!kt4 || dt < 5) { WAITVM8; }
            else if (dt == 5)   { WAITVM4; }
            else                { WAITVM0; }
            short8 n0r, n1r, n2r, n3r;
            if (!kt4 || dt < 7) {               // read next chunk's fragments (latency hides under MFMA)
                const short* esb = uni + wbase + bufr1 * 2048;
                n0r = *(const short8*)(esb + ( 0 + lr) * 32 + sw8);
                n1r = *(const short8*)(esb + (16 + lr) * 32 + sw8);
                n2r = *(const short8*)(esb + (32 + lr) * 32 + sw8);
                n3r = *(const short8*)(esb + (48 + lr) * 32 + sw8);
            }
            __builtin_amdgcn_s_setprio(1);
#pragma unroll
            for (int mt = 0; mt < 4; ++mt) {
                acc[mt][0] = __builtin_amdgcn_mfma_f32_16x16x32_bf16(af[mt][dt], c0, acc[mt][0], 0, 0, 0);
                acc[mt][1] = __builtin_amdgcn_mfma_f32_16x16x32_bf16(af[mt][dt], c1, acc[mt][1], 0, 0, 0);
                acc[mt][2] = __builtin_amdgcn_mfma_f32_16x16x32_bf16(af[mt][dt], c2, acc[mt][2], 0, 0, 0);
                acc[mt][3] = __builtin_amdgcn_mfma_f32_16x16x32_bf16(af[mt][dt], c3, acc[mt][3], 0, 0, 0);
            }
            __builtin_amdgcn_s_setprio(0);
            if (!kt4 || dt < 7) { c0 = n0r; c1 = n1r; c2 = n2r; c3 = n3r; }
            bufr = bufr1;
        }

        if (kt == 0) {
            // one-time threshold: wave-local max over 64 k, cross-wave combine (only 2 barriers in loop)
            float mx[4][4];
#pragma unroll
            for (int mt = 0; mt < 4; ++mt)
#pragma unroll
                for (int r = 0; r < 4; ++r)
                    mx[mt][r] = fmaxf(fmaxf(acc[mt][0][r], acc[mt][1][r]),
                                      fmaxf(acc[mt][2][r], acc[mt][3][r]));
#pragma unroll
            for (int s = 1; s <= 8; s <<= 1)
#pragma unroll
                for (int mt = 0; mt < 4; ++mt)
#pragma unroll
                    for (int r = 0; r < 4; ++r)
                        mx[mt][r] = fmaxf(mx[mt][r], __shfl_xor(mx[mt][r], s, 64));
#pragma unroll
            for (int mt = 0; mt < 4; ++mt)
#pragma unroll
                for (int r = 0; r < 4; ++r)
                    if (lr == mt * 4 + r)
                        maxred[(16 * mt + 4 * lq + r) * 4 + w] = mx[mt][r];
            WAITLG0; __builtin_amdgcn_s_barrier(); MEMBAR;
            if (tid < 64) {
                float a = fmaxf(fmaxf(maxred[tid * 4 + 0], maxred[tid * 4 + 1]),
                                fmaxf(maxred[tid * 4 + 2], maxred[tid * 4 + 3]));
                thrS[tid] = a - epsS[tid];      // sound: thr <= trueMax - eps
            }
            WAITLG0; __builtin_amdgcn_s_barrier(); MEMBAR;
        } else {
            // record candidates (kt0's k covered by the kt4 redo)
#pragma unroll
            for (int mt = 0; mt < 4; ++mt)
#pragma unroll
                for (int r = 0; r < 4; ++r) {
                    int row = 16 * mt + 4 * lq + r;
                    float th = thrS[row];
                    float m4 = fmaxf(fmaxf(acc[mt][0][r], acc[mt][1][r]),
                                     fmaxf(acc[mt][2][r], acc[mt][3][r]));
                    if (m4 >= th) {
#pragma unroll
                        for (int nt = 0; nt < 4; ++nt)
                            if (acc[mt][nt][r] >= th) {
                                int kk = kb + 16 * nt + lr;
                                unsigned int p = atomicAdd(&cntS[row], 1u);
                                if (p < 32u) cl[row * 32 + p] = kk;
                                else atomicMax(&ovfS, 1);
                            }
                    }
                }
        }

        if (kt < 4) {   // re-init acc = -e2/2 for next k-tile
            const int nb = kt + 1;
            const int kbn = wq + ((nb < 4 ? nb : 0) << 6);
#pragma unroll
            for (int nt = 0; nt < 4; ++nt) {
                float e = e2hS[kbn + 16 * nt + lr];
                f32x4 iv = { -e, -e, -e, -e };
#pragma unroll
                for (int mt = 0; mt < 4; ++mt) acc[mt][nt] = iv;
            }
        }
    }

    // ---------------- exact recheck (bit-identical fp32 chain) ----------------
    __syncthreads();
    float* zx = (float*)uni;                 // [32 dd][68] fp32 chunk, reuse union region
    const int pt = tid & 63;
    const int s0 = tid >> 6;                 // 4 slot-threads per point
    unsigned int nc = cntS[pt]; if (nc > 32u) nc = 32u;
    bool  act[8]; int kE[8]; float accE[8];
#pragma unroll
    for (int j = 0; j < 8; ++j) {
        unsigned int s = (unsigned int)s0 + 4u * j;
        act[j] = s < nc;
        kE[j] = act[j] ? cl[pt * 32 + s] : 0;
        accE[j] = 0.0f;
    }
#pragma unroll 1
    for (int dt = 0; dt < 8; ++dt) {
        const int dbase = dt * 32;
        __syncthreads();
        {
            int q = tid & 15, dd0 = tid >> 4;
            float4 v0 = *(const float4*)(z + zb + ((dbase + dd0) << 10) + 4 * q);
            float4 v1 = *(const float4*)(z + zb + ((dbase + dd0 + 16) << 10) + 4 * q);
            *(float4*)(zx + dd0 * 68 + 4 * q) = v0;
            *(float4*)(zx + (dd0 + 16) * 68 + 4 * q) = v1;
        }
        __syncthreads();
#pragma unroll
        for (int j = 0; j < 8; ++j) {
            if (!act[j]) continue;
            const float* er = emb + kE[j] * 256 + dbase;
            float ev[32];
#pragma unroll
            for (int c = 0; c < 8; ++c) *(float4*)(ev + 4 * c) = *(const float4*)(er + 4 * c);
            float a = accE[j];
#pragma unroll
            for (int dd = 0; dd < 32; ++dd)
                a = __builtin_fmaf(zx[dd * 68 + pt], ev[dd], a);
            accE[j] = a;
        }
    }
#pragma unroll
    for (int j = 0; j < 8; ++j) {
        if (!act[j]) continue;
        int k = kE[j];
        float t1 = __fadd_rn(z2S[pt], e2w[k]);
        float d  = __fsub_rn(t1, __fmul_rn(2.0f, accE[j]));
        atomicMin(&bestS[pt], pack_vi(d, k));
    }
    __syncthreads();

    if (ovfS) {   // near-impossible fallback: full exact scan for overflowed points
        for (int row = 0; row < 64; ++row) {
            if (cntS[row] <= 32u) continue;
            float fa[4] = {0.f, 0.f, 0.f, 0.f};
            for (int dt = 0; dt < 8; ++dt) {
                const int dbase = dt * 32;
                __syncthreads();
                {
                    int q = tid & 15, dd0 = tid >> 4;
                    float4 v0 = *(const float4*)(z + zb + ((dbase + dd0) << 10) + 4 * q);
                    float4 v1 = *(const float4*)(z + zb + ((dbase + dd0 + 16) << 10) + 4 * q);
                    *(float4*)(zx + dd0 * 68 + 4 * q) = v0;
                    *(float4*)(zx + (dd0 + 16) * 68 + 4 * q) = v1;
                }
                __syncthreads();
                for (int c = 0; c < 4; ++c) {
                    const float* er = emb + (tid + 256 * c) * 256 + dbase;
                    for (int dd = 0; dd < 32; ++dd)
                        fa[c] = __builtin_fmaf(zx[dd * 68 + row], er[dd], fa[c]);
                }
            }
            for (int c = 0; c < 4; ++c) {
                int k = tid + 256 * c;
                float t1 = __fadd_rn(z2S[row], e2w[k]);
                float d  = __fsub_rn(t1, __fmul_rn(2.0f, fa[c]));
                atomicMin(&bestS[row], pack_vi(d, k));
            }
            __syncthreads();
        }
    }

    if (tid < 64)
        out_idx[n0 + tid] = (float)(unsigned int)(bestS[tid] & 0xFFFFFFFFULL);
}

// 256 blocks (was 128 = half the CUs idle): each block 128 points, d split in halves.
__global__ __launch_bounds__(256) void zq_loss_kernel(
    const float* __restrict__ z, const float* __restrict__ emb,
    const float* __restrict__ idxv, float* __restrict__ zq,
    double* __restrict__ loss_acc, unsigned int* __restrict__ ticket,
    float* __restrict__ out_loss)
{
    const int tl = threadIdx.x & 127;
    const int h  = threadIdx.x >> 7;         // d-half
    const int n  = blockIdx.x * 128 + tl;
    const int kk = (int)idxv[n];
    const float* er = emb + kk * DIM + (h << 7);
    const int zb2 = z_base(n) + (h << 17);   // + (h*128)<<10
    double s = 0.0;
#pragma unroll 8
    for (int dd = 0; dd < 128; ++dd) {
        float ev = er[dd];
        float zv = z[zb2 + (dd << 10)];
        zq[zb2 + (dd << 10)] = ev;
        float df = ev - zv;
        s = fma((double)df, (double)df, s);
    }
    for (int off = 32; off; off >>= 1) s += __shfl_down(s, off, 64);
    __shared__ double sred[4];
    if ((threadIdx.x & 63) == 0) sred[threadIdx.x >> 6] = s;
    __syncthreads();
    if (threadIdx.x == 0) {
        atomicAdd(loss_acc, (sred[0] + sred[1]) + (sred[2] + sred[3]));
        __threadfence();
        unsigned int old = atomicAdd(ticket, 1u);
        if (old == gridDim.x - 1) {
            double total = atomicAdd(loss_acc, 0.0);
            out_loss[0] = (float)(1.25 * (total / 8388608.0));
        }
    }
}

extern "C" void kernel_launch(void* const* d_in, const int* in_sizes, int n_in,
                              void* d_out, int out_size, void* d_ws, size_t ws_size,
                              hipStream_t stream) {
    const float* z   = (const float*)d_in[0];
    const float* emb = (const float*)d_in[1];
    float* out = (float*)d_out;

    // ws: z2[32768]f32 @0 | eps[32768]f32 @131072 | e2[1024] @262144 |
    //     e2h[1024] @266240 | ebf16(chunked) @270336 | loss f64 @794624 | ticket @794632
    float* z2w = (float*)d_ws;
    float* epsw = (float*)((char*)d_ws + 131072);
    float* e2w = (float*)((char*)d_ws + 262144);
    float* e2hw = (float*)((char*)d_ws + 266240);
    ushort_t* ebf = (ushort_t*)((char*)d_ws + 270336);
    double* loss_acc = (double*)((char*)d_ws + 794624);
    unsigned int* ticket = (unsigned int*)((char*)d_ws + 794632);

    setup_kernel<<<132, 256, 0, stream>>>(z, emb, z2w, epsw, e2w, e2hw, ebf,
                                          loss_acc, ticket);
    dist_kernel<<<NPTS / 64, 256, 0, stream>>>(z, emb, ebf, z2w, e2w, e2hw, epsw,
                                               out + IDX_OFF);
    zq_loss_kernel<<<256, 256, 0, stream>>>(z, emb, out + IDX_OFF,
                                            out + ZQ_OFF, loss_acc, ticket,
                                            out + LOSS_OFF);
}

// Round 2
// 389.460 us; speedup vs baseline: 1.0723x; 1.0723x over previous
//
#include <hip/hip_runtime.h>

#define NPTS  32768
#define DIM   256

#define ZQ_OFF   0
#define LOSS_OFF 8388608
#define IDX_OFF  8388609

typedef __attribute__((ext_vector_type(8))) short short8;
typedef __attribute__((ext_vector_type(4))) float f32x4;
typedef unsigned short ushort_t;
typedef unsigned int u32;

// z layout [B, D, H, W]: point n = b*1024 + h*32 + w ; elem (n,d) at b*262144 + d*1024 + hw
__device__ __forceinline__ int z_base(int n) { return ((n >> 10) << 18) | (n & 1023); }

// RNE float->bf16 (bits)
__device__ __forceinline__ ushort_t f2bf(float f) {
    u32 u = __float_as_uint(f);
    u += 0x7FFFu + ((u >> 16) & 1u);
    return (ushort_t)(u >> 16);
}

__device__ __forceinline__ unsigned long long pack_vi(float v, int i) {
    u32 u = __float_as_uint(v);
    u32 key = (u & 0x80000000u) ? ~u : u;   // monotone float->uint (finite)
    return ((unsigned long long)key << 32) | (u32)i;
}

// ---- numpy pairwise sum (AVX512 npyv order) of squares, 128 elems ----
__device__ __forceinline__ float np_half_sq(const float* __restrict__ p, int stride) {
    float S[16];
#pragma unroll
    for (int l = 0; l < 16; ++l) {
        float t[8];
#pragma unroll
        for (int j = 0; j < 8; ++j) {
            float v = p[(j * 16 + l) * stride];
            t[j] = __fmul_rn(v, v);
        }
        S[l] = __fadd_rn(__fadd_rn(__fadd_rn(t[0], t[1]), __fadd_rn(t[2], t[3])),
                         __fadd_rn(__fadd_rn(t[4], t[5]), __fadd_rn(t[6], t[7])));
    }
    float u[8];
#pragma unroll
    for (int i = 0; i < 8; ++i) u[i] = __fadd_rn(S[i], S[i + 8]);
    float v4[4];
#pragma unroll
    for (int i = 0; i < 4; ++i) v4[i] = __fadd_rn(u[i], u[i + 4]);
    return __fadd_rn(__fadd_rn(v4[0], v4[2]), __fadd_rn(v4[1], v4[3]));
}
__device__ __forceinline__ float np_sum256_sq(const float* __restrict__ p, int stride) {
    return __fadd_rn(np_half_sq(p, stride), np_half_sq(p + 128 * stride, stride));
}

// same square chain (bit-identical z2), abs-sum fused into the same pass (order-free bound input)
__device__ __forceinline__ float np_half_sq_abs(const float* __restrict__ p, int stride, float* aacc) {
    float S[16]; float a = *aacc;
#pragma unroll
    for (int l = 0; l < 16; ++l) {
        float t[8];
#pragma unroll
        for (int j = 0; j < 8; ++j) {
            float v = p[(j * 16 + l) * stride];
            t[j] = __fmul_rn(v, v);
            a = __fadd_rn(a, fabsf(v));
        }
        S[l] = __fadd_rn(__fadd_rn(__fadd_rn(t[0], t[1]), __fadd_rn(t[2], t[3])),
                         __fadd_rn(__fadd_rn(t[4], t[5]), __fadd_rn(t[6], t[7])));
    }
    float u[8];
#pragma unroll
    for (int i = 0; i < 8; ++i) u[i] = __fadd_rn(S[i], S[i + 8]);
    float v4[4];
#pragma unroll
    for (int i = 0; i < 4; ++i) v4[i] = __fadd_rn(u[i], u[i + 4]);
    *aacc = a;
    return __fadd_rn(__fadd_rn(v4[0], v4[2]), __fadd_rn(v4[1], v4[3]));
}

// blocks 0..127: per-point z2 (np order) + fused abs-sum -> eps (single z pass).
// blocks 128..131: e2/e2h + swizzled chunked bf16 image of emb for global_load_lds:
//   chunk (kc,dt) = 4KB covering k in [kc*64,+64), d in [dt*32,+32).
//   within chunk, 16B slot s (0..255): row=s>>2, sl=s&3, lq=sl^((row>>1)&3),
//   holds bf16 emb[kc*64+row][dt*32 + lq*8 .. +7]  (XOR bank swizzle baked in).
__global__ __launch_bounds__(256) void setup_kernel(
    const float* __restrict__ z, const float* __restrict__ emb,
    float* __restrict__ z2, float* __restrict__ eps,
    float* __restrict__ e2, float* __restrict__ e2h,
    ushort_t* __restrict__ ebf,
    double* __restrict__ loss_acc, unsigned int* __restrict__ ticket)
{
    if (blockIdx.x < 128) {
        int n = blockIdx.x * 256 + threadIdx.x;
        const float* p = z + z_base(n);
        float a = 0.0f;
        float h0 = np_half_sq_abs(p, 1024, &a);
        float h1 = np_half_sq_abs(p + 128 * 1024, 1024, &a);
        z2[n] = __fadd_rn(h0, h1);
        eps[n] = __builtin_fmaf(1e-5f, a, 3e-4f);   // sound |d~ - d| bound
        if (blockIdx.x == 0 && threadIdx.x == 0) { *loss_acc = 0.0; *ticket = 0u; }
    } else {
        int kb = (blockIdx.x - 128) * 256;
        for (int i = threadIdx.x; i < 8192; i += 256) {
            int c = i >> 8, s = i & 255;
            int kcl = c >> 3, dtc = c & 7;
            int row = s >> 2, sl = s & 3;
            int lq = sl ^ ((row >> 1) & 3);
            int k = kb + (kcl << 6) + row;
            int d0 = dtc * 32 + lq * 8;
            const float* e = emb + k * 256 + d0;
            short8 ov;
#pragma unroll
            for (int j = 0; j < 8; ++j) ov[j] = (short)f2bf(e[j]);
            *(short8*)(ebf + ((((kb >> 6) + kcl) << 3) + dtc) * 2048 + (s << 3)) = ov;
        }
        int k = kb + threadIdx.x;
        float s = np_sum256_sq(emb + k * DIM, 1);
        e2[k] = s;
        e2h[k] = 0.5f * s;
    }
}

// ---------------- MFMA distance + candidate filter + exact recheck ----------------
// block: 64 points x 1024 k. 4 waves; each wave owns a 256-k quarter (barrier-free main loop,
// 2 barriers total for the one-time threshold). A-fragments read per-step from persistent LDS zs
// (4 ds_read_b128, pad-264 = conflict-optimal); es = per-wave 2x4KB double buffer staged with
// global_load_lds, counted vmcnt(4), drained to 0 only on the last step.
#define ZS_STRIDE 264
#define ES_SH     16896     // short offset of es region within uni

__device__ __forceinline__ void async_cp16(const ushort_t* g, ushort_t* l) {
    __builtin_amdgcn_global_load_lds(
        (const __attribute__((address_space(1))) u32*)g,
        (__attribute__((address_space(3))) u32*)l, 16, 0, 0);
}

#define WAITVM4 asm volatile("s_waitcnt vmcnt(4)" ::: "memory")
#define WAITVM0 asm volatile("s_waitcnt vmcnt(0)" ::: "memory")
#define WAITLG0 asm volatile("s_waitcnt lgkmcnt(0)" ::: "memory")
#define MEMBAR  asm volatile("" ::: "memory")

__global__ __launch_bounds__(256, 2) void dist_kernel(
    const float* __restrict__ z, const float* __restrict__ emb,
    const ushort_t* __restrict__ ebf,
    const float* __restrict__ z2w, const float* __restrict__ e2w,
    const float* __restrict__ e2hw, const float* __restrict__ epsw,
    float* __restrict__ out_idx)
{
    // uni: zs [64][264] bf16 persistent (33792B) | es 4w x 2buf x 4KB (32768B). 66560B total.
    __shared__ __align__(16) short uni[33280];
    __shared__ __align__(16) int cl[2048];      // candidate lists; first 256 floats alias maxred
    __shared__ float e2hS[1024];
    __shared__ float thrS[64], epsS[64], z2S[64];
    __shared__ unsigned int cntS[64];
    __shared__ unsigned long long bestS[64];
    __shared__ int ovfS;

    const int tid = threadIdx.x;
    const int w  = tid >> 6;       // wave 0..3
    const int l  = tid & 63;
    const int lq = l >> 4;
    const int lr = l & 15;
    const int sw8 = ((lq ^ ((lr >> 1) & 3)) << 3);   // swizzled B slot (short offset)
    const int n0 = blockIdx.x << 6;
    const int zb = z_base(n0);
    const int wq = w << 8;                            // wave k base (0,256,512,768)
    const int wes = ES_SH + (w << 12);                // wave es base (shorts)

    if (tid < 64) {
        cntS[tid] = 0u; bestS[tid] = 0x7FFFFFFFFFFFFFFFULL;
        epsS[tid] = epsw[n0 + tid]; z2S[tid] = z2w[n0 + tid];
    }
    if (tid == 0) ovfS = 0;
    for (int i = tid; i < 1024; i += 256) e2hS[i] = e2hw[i];

    // stage zs (fp32 -> bf16, transpose to [pt][d]); persistent for the whole loop
    {
        short* zs = uni;
        int q = tid & 15, d0 = tid >> 4;
#pragma unroll 4
        for (int i = 0; i < 16; ++i) {
            int d = d0 + 16 * i;
            float4 v = *(const float4*)(z + zb + (d << 10) + 4 * q);
            zs[(4 * q + 0) * ZS_STRIDE + d] = (short)f2bf(v.x);
            zs[(4 * q + 1) * ZS_STRIDE + d] = (short)f2bf(v.y);
            zs[(4 * q + 2) * ZS_STRIDE + d] = (short)f2bf(v.z);
            zs[(4 * q + 3) * ZS_STRIDE + d] = (short)f2bf(v.w);
        }
    }
    __syncthreads();

    f32x4 acc[4][4];
#pragma unroll
    for (int nt = 0; nt < 4; ++nt) {
        float e = e2hS[wq + 16 * nt + lr];
        f32x4 iv = { -e, -e, -e, -e };
#pragma unroll
        for (int mt = 0; mt < 4; ++mt) acc[mt][nt] = iv;
    }

    // prologue: issue chunk 0 (kt0, dt0) into buf 0
    {
        const ushort_t* gs = ebf + (((w << 2) << 3) << 11) + (l << 3);
        ushort_t* ld = (ushort_t*)(uni + wes);
        async_cp16(gs,        ld);
        async_cp16(gs +  512, ld +  512);
        async_cp16(gs + 1024, ld + 1024);
        async_cp16(gs + 1536, ld + 1536);
    }

#pragma unroll 1
    for (int g = 0; g < 40; ++g) {                 // kt 0..4 (kt4 = kt0 redo) x dt 0..7
        const int kt = g >> 3, dt = g & 7;
        if (g < 39) {                              // issue chunk g+1 into the other buffer
            const int gn = g + 1;
            const int ktn = gn >> 3, dtn = gn & 7;
            const int kcn = (w << 2) + (ktn < 4 ? ktn : 0);
            const ushort_t* gs = ebf + ((((kcn << 3) + dtn)) << 11) + (l << 3);
            ushort_t* ld = (ushort_t*)(uni + wes + ((gn & 1) << 11));
            async_cp16(gs,        ld);
            async_cp16(gs +  512, ld +  512);
            async_cp16(gs + 1024, ld + 1024);
            async_cp16(gs + 1536, ld + 1536);
        }
        // A-fragments from persistent zs (no vmcnt dependency; overlaps the wait)
        const short* zrow = uni + lr * ZS_STRIDE + dt * 32 + lq * 8;
        short8 a0 = *(const short8*)(zrow);
        short8 a1 = *(const short8*)(zrow + 16 * ZS_STRIDE);
        short8 a2 = *(const short8*)(zrow + 32 * ZS_STRIDE);
        short8 a3 = *(const short8*)(zrow + 48 * ZS_STRIDE);
        if (g < 39) { WAITVM4; } else { WAITVM0; } // chunk g landed; g+1 stays in flight
        const short* esb = uni + wes + ((g & 1) << 11);
        short8 b0 = *(const short8*)(esb + ( 0 + lr) * 32 + sw8);
        short8 b1 = *(const short8*)(esb + (16 + lr) * 32 + sw8);
        short8 b2 = *(const short8*)(esb + (32 + lr) * 32 + sw8);
        short8 b3 = *(const short8*)(esb + (48 + lr) * 32 + sw8);
        __builtin_amdgcn_s_setprio(1);
        acc[0][0] = __builtin_amdgcn_mfma_f32_16x16x32_bf16(a0, b0, acc[0][0], 0, 0, 0);
        acc[0][1] = __builtin_amdgcn_mfma_f32_16x16x32_bf16(a0, b1, acc[0][1], 0, 0, 0);
        acc[0][2] = __builtin_amdgcn_mfma_f32_16x16x32_bf16(a0, b2, acc[0][2], 0, 0, 0);
        acc[0][3] = __builtin_amdgcn_mfma_f32_16x16x32_bf16(a0, b3, acc[0][3], 0, 0, 0);
        acc[1][0] = __builtin_amdgcn_mfma_f32_16x16x32_bf16(a1, b0, acc[1][0], 0, 0, 0);
        acc[1][1] = __builtin_amdgcn_mfma_f32_16x16x32_bf16(a1, b1, acc[1][1], 0, 0, 0);
        acc[1][2] = __builtin_amdgcn_mfma_f32_16x16x32_bf16(a1, b2, acc[1][2], 0, 0, 0);
        acc[1][3] = __builtin_amdgcn_mfma_f32_16x16x32_bf16(a1, b3, acc[1][3], 0, 0, 0);
        acc[2][0] = __builtin_amdgcn_mfma_f32_16x16x32_bf16(a2, b0, acc[2][0], 0, 0, 0);
        acc[2][1] = __builtin_amdgcn_mfma_f32_16x16x32_bf16(a2, b1, acc[2][1], 0, 0, 0);
        acc[2][2] = __builtin_amdgcn_mfma_f32_16x16x32_bf16(a2, b2, acc[2][2], 0, 0, 0);
        acc[2][3] = __builtin_amdgcn_mfma_f32_16x16x32_bf16(a2, b3, acc[2][3], 0, 0, 0);
        acc[3][0] = __builtin_amdgcn_mfma_f32_16x16x32_bf16(a3, b0, acc[3][0], 0, 0, 0);
        acc[3][1] = __builtin_amdgcn_mfma_f32_16x16x32_bf16(a3, b1, acc[3][1], 0, 0, 0);
        acc[3][2] = __builtin_amdgcn_mfma_f32_16x16x32_bf16(a3, b2, acc[3][2], 0, 0, 0);
        acc[3][3] = __builtin_amdgcn_mfma_f32_16x16x32_bf16(a3, b3, acc[3][3], 0, 0, 0);
        __builtin_amdgcn_s_setprio(0);

        if (dt == 7) {
            if (kt == 0) {
                // one-time threshold: wave-local max over its 64 k, cross-wave combine
                float* maxred = (float*)cl;          // alias: cl written only at kt>=1
                float mx[4][4];
#pragma unroll
                for (int mt = 0; mt < 4; ++mt)
#pragma unroll
                    for (int r = 0; r < 4; ++r)
                        mx[mt][r] = fmaxf(fmaxf(acc[mt][0][r], acc[mt][1][r]),
                                          fmaxf(acc[mt][2][r], acc[mt][3][r]));
#pragma unroll
                for (int s = 1; s <= 8; s <<= 1)
#pragma unroll
                    for (int mt = 0; mt < 4; ++mt)
#pragma unroll
                        for (int r = 0; r < 4; ++r)
                            mx[mt][r] = fmaxf(mx[mt][r], __shfl_xor(mx[mt][r], s, 64));
#pragma unroll
                for (int mt = 0; mt < 4; ++mt)
#pragma unroll
                    for (int r = 0; r < 4; ++r)
                        if (lr == mt * 4 + r)
                            maxred[(16 * mt + 4 * lq + r) * 4 + w] = mx[mt][r];
                WAITLG0; __builtin_amdgcn_s_barrier(); MEMBAR;
                if (tid < 64) {
                    float a = fmaxf(fmaxf(maxred[tid * 4 + 0], maxred[tid * 4 + 1]),
                                    fmaxf(maxred[tid * 4 + 2], maxred[tid * 4 + 3]));
                    thrS[tid] = a - epsS[tid];       // sound: thr <= trueMax - eps
                }
                WAITLG0; __builtin_amdgcn_s_barrier(); MEMBAR;
            } else {
                // record candidates (kt0's k covered by the kt4 redo)
                const int kb = wq + ((kt < 4 ? kt : 0) << 6);
#pragma unroll
                for (int mt = 0; mt < 4; ++mt)
#pragma unroll
                    for (int r = 0; r < 4; ++r) {
                        int row = 16 * mt + 4 * lq + r;
                        float th = thrS[row];
                        float m4 = fmaxf(fmaxf(acc[mt][0][r], acc[mt][1][r]),
                                         fmaxf(acc[mt][2][r], acc[mt][3][r]));
                        if (m4 >= th) {
#pragma unroll
                            for (int nt = 0; nt < 4; ++nt)
                                if (acc[mt][nt][r] >= th) {
                                    int kk = kb + 16 * nt + lr;
                                    unsigned int p = atomicAdd(&cntS[row], 1u);
                                    if (p < 32u) cl[row * 32 + p] = kk;
                                    else atomicMax(&ovfS, 1);
                                }
                        }
                    }
            }
            if (kt < 4) {   // re-init acc = -e2/2 for the next k-tile
                const int nb = kt + 1;
                const int kbn = wq + ((nb < 4 ? nb : 0) << 6);
#pragma unroll
                for (int nt = 0; nt < 4; ++nt) {
                    float e = e2hS[kbn + 16 * nt + lr];
                    f32x4 iv = { -e, -e, -e, -e };
#pragma unroll
                    for (int mt = 0; mt < 4; ++mt) acc[mt][nt] = iv;
                }
            }
        }
    }

    // ---------------- exact recheck (bit-identical fp32 chain) ----------------
    __syncthreads();
    float* zx = (float*)uni;                 // [32 dd][68] fp32 chunk; zs/es are dead
    const int pt = tid & 63;
    const int s0 = tid >> 6;                 // 4 slot-threads per point
    unsigned int nc = cntS[pt]; if (nc > 32u) nc = 32u;
    bool  act[8]; int kE[8]; float accE[8];
#pragma unroll
    for (int j = 0; j < 8; ++j) {
        unsigned int s = (unsigned int)s0 + 4u * j;
        act[j] = s < nc;
        kE[j] = act[j] ? cl[pt * 32 + s] : 0;
        accE[j] = 0.0f;
    }
#pragma unroll 1
    for (int dt = 0; dt < 8; ++dt) {
        const int dbase = dt * 32;
        __syncthreads();
        {
            int q = tid & 15, dd0 = tid >> 4;
            float4 v0 = *(const float4*)(z + zb + ((dbase + dd0) << 10) + 4 * q);
            float4 v1 = *(const float4*)(z + zb + ((dbase + dd0 + 16) << 10) + 4 * q);
            *(float4*)(zx + dd0 * 68 + 4 * q) = v0;
            *(float4*)(zx + (dd0 + 16) * 68 + 4 * q) = v1;
        }
        __syncthreads();
#pragma unroll
        for (int j = 0; j < 8; ++j) {
            if (!act[j]) continue;
            const float* er = emb + kE[j] * 256 + dbase;
            float ev[32];
#pragma unroll
            for (int c = 0; c < 8; ++c) *(float4*)(ev + 4 * c) = *(const float4*)(er + 4 * c);
            float a = accE[j];
#pragma unroll
            for (int dd = 0; dd < 32; ++dd)
                a = __builtin_fmaf(zx[dd * 68 + pt], ev[dd], a);
            accE[j] = a;
        }
    }
#pragma unroll
    for (int j = 0; j < 8; ++j) {
        if (!act[j]) continue;
        int k = kE[j];
        float t1 = __fadd_rn(z2S[pt], e2w[k]);
        float d  = __fsub_rn(t1, __fmul_rn(2.0f, accE[j]));
        atomicMin(&bestS[pt], pack_vi(d, k));
    }
    __syncthreads();

    if (ovfS) {   // near-impossible fallback: full exact scan for overflowed points
        for (int row = 0; row < 64; ++row) {
            if (cntS[row] <= 32u) continue;
            float fa[4] = {0.f, 0.f, 0.f, 0.f};
            for (int dt = 0; dt < 8; ++dt) {
                const int dbase = dt * 32;
                __syncthreads();
                {
                    int q = tid & 15, dd0 = tid >> 4;
                    float4 v0 = *(const float4*)(z + zb + ((dbase + dd0) << 10) + 4 * q);
                    float4 v1 = *(const float4*)(z + zb + ((dbase + dd0 + 16) << 10) + 4 * q);
                    *(float4*)(zx + dd0 * 68 + 4 * q) = v0;
                    *(float4*)(zx + (dd0 + 16) * 68 + 4 * q) = v1;
                }
                __syncthreads();
                for (int c = 0; c < 4; ++c) {
                    const float* er = emb + (tid + 256 * c) * 256 + dbase;
                    for (int dd = 0; dd < 32; ++dd)
                        fa[c] = __builtin_fmaf(zx[dd * 68 + row], er[dd], fa[c]);
                }
            }
            for (int c = 0; c < 4; ++c) {
                int k = tid + 256 * c;
                float t1 = __fadd_rn(z2S[row], e2w[k]);
                float d  = __fsub_rn(t1, __fmul_rn(2.0f, fa[c]));
                atomicMin(&bestS[row], pack_vi(d, k));
            }
            __syncthreads();
        }
    }

    if (tid < 64)
        out_idx[n0 + tid] = (float)(unsigned int)(bestS[tid] & 0xFFFFFFFFULL);
}

// 256 blocks: each block 128 points, d split in halves across the two thread-halves.
__global__ __launch_bounds__(256) void zq_loss_kernel(
    const float* __restrict__ z, const float* __restrict__ emb,
    const float* __restrict__ idxv, float* __restrict__ zq,
    double* __restrict__ loss_acc, unsigned int* __restrict__ ticket,
    float* __restrict__ out_loss)
{
    const int tl = threadIdx.x & 127;
    const int h  = threadIdx.x >> 7;         // d-half
    const int n  = blockIdx.x * 128 + tl;
    const int kk = (int)idxv[n];
    const float* er = emb + kk * DIM + (h << 7);
    const int zb2 = z_base(n) + (h << 17);   // + (h*128)<<10
    double s = 0.0;
#pragma unroll 8
    for (int dd = 0; dd < 128; ++dd) {
        float ev = er[dd];
        float zv = z[zb2 + (dd << 10)];
        zq[zb2 + (dd << 10)] = ev;
        float df = ev - zv;
        s = fma((double)df, (double)df, s);
    }
    for (int off = 32; off; off >>= 1) s += __shfl_down(s, off, 64);
    __shared__ double sred[4];
    if ((threadIdx.x & 63) == 0) sred[threadIdx.x >> 6] = s;
    __syncthreads();
    if (threadIdx.x == 0) {
        atomicAdd(loss_acc, (sred[0] + sred[1]) + (sred[2] + sred[3]));
        __threadfence();
        unsigned int old = atomicAdd(ticket, 1u);
        if (old == gridDim.x - 1) {
            double total = atomicAdd(loss_acc, 0.0);
            out_loss[0] = (float)(1.25 * (total / 8388608.0));
        }
    }
}

extern "C" void kernel_launch(void* const* d_in, const int* in_sizes, int n_in,
                              void* d_out, int out_size, void* d_ws, size_t ws_size,
                              hipStream_t stream) {
    const float* z   = (const float*)d_in[0];
    const float* emb = (const float*)d_in[1];
    float* out = (float*)d_out;

    // ws: z2[32768]f32 @0 | eps[32768]f32 @131072 | e2[1024] @262144 |
    //     e2h[1024] @266240 | ebf16(chunked) @270336 | loss f64 @794624 | ticket @794632
    float* z2w = (float*)d_ws;
    float* epsw = (float*)((char*)d_ws + 131072);
    float* e2w = (float*)((char*)d_ws + 262144);
    float* e2hw = (float*)((char*)d_ws + 266240);
    ushort_t* ebf = (ushort_t*)((char*)d_ws + 270336);
    double* loss_acc = (double*)((char*)d_ws + 794624);
    unsigned int* ticket = (unsigned int*)((char*)d_ws + 794632);

    setup_kernel<<<132, 256, 0, stream>>>(z, emb, z2w, epsw, e2w, e2hw, ebf,
                                          loss_acc, ticket);
    dist_kernel<<<NPTS / 64, 256, 0, stream>>>(z, emb, ebf, z2w, e2w, e2hw, epsw,
                                               out + IDX_OFF);
    zq_loss_kernel<<<256, 256, 0, stream>>>(z, emb, out + IDX_OFF,
                                            out + ZQ_OFF, loss_acc, ticket,
                                            out + LOSS_OFF);
}

// Round 3
// 232.671 us; speedup vs baseline: 1.7949x; 1.6739x over previous
//
#include <hip/hip_runtime.h>

#define NPTS  32768
#define DIM   256

#define ZQ_OFF   0
#define LOSS_OFF 8388608
#define IDX_OFF  8388609

typedef __attribute__((ext_vector_type(8))) short short8;
typedef __attribute__((ext_vector_type(4))) float f32x4;
typedef unsigned short ushort_t;
typedef unsigned int u32;

// z layout [B, D, H, W]: point n = b*1024 + h*32 + w ; elem (n,d) at b*262144 + d*1024 + hw
__device__ __forceinline__ int z_base(int n) { return ((n >> 10) << 18) | (n & 1023); }

// RNE float->bf16 (bits)
__device__ __forceinline__ ushort_t f2bf(float f) {
    u32 u = __float_as_uint(f);
    u += 0x7FFFu + ((u >> 16) & 1u);
    return (ushort_t)(u >> 16);
}

__device__ __forceinline__ unsigned long long pack_vi(float v, int i) {
    u32 u = __float_as_uint(v);
    u32 key = (u & 0x80000000u) ? ~u : u;   // monotone float->uint (finite)
    return ((unsigned long long)key << 32) | (u32)i;
}

// ---- numpy pairwise sum (AVX512 npyv order) of squares, 128 elems ----
__device__ __forceinline__ float np_half_sq(const float* __restrict__ p, int stride) {
    float S[16];
#pragma unroll
    for (int l = 0; l < 16; ++l) {
        float t[8];
#pragma unroll
        for (int j = 0; j < 8; ++j) {
            float v = p[(j * 16 + l) * stride];
            t[j] = __fmul_rn(v, v);
        }
        S[l] = __fadd_rn(__fadd_rn(__fadd_rn(t[0], t[1]), __fadd_rn(t[2], t[3])),
                         __fadd_rn(__fadd_rn(t[4], t[5]), __fadd_rn(t[6], t[7])));
    }
    float u[8];
#pragma unroll
    for (int i = 0; i < 8; ++i) u[i] = __fadd_rn(S[i], S[i + 8]);
    float v4[4];
#pragma unroll
    for (int i = 0; i < 4; ++i) v4[i] = __fadd_rn(u[i], u[i + 4]);
    return __fadd_rn(__fadd_rn(v4[0], v4[2]), __fadd_rn(v4[1], v4[3]));
}
__device__ __forceinline__ float np_sum256_sq(const float* __restrict__ p, int stride) {
    return __fadd_rn(np_half_sq(p, stride), np_half_sq(p + 128 * stride, stride));
}

// same square chain (bit-identical z2), abs-sum fused into the same pass (order-free bound input)
__device__ __forceinline__ float np_half_sq_abs(const float* __restrict__ p, int stride, float* aacc) {
    float S[16]; float a = *aacc;
#pragma unroll
    for (int l = 0; l < 16; ++l) {
        float t[8];
#pragma unroll
        for (int j = 0; j < 8; ++j) {
            float v = p[(j * 16 + l) * stride];
            t[j] = __fmul_rn(v, v);
            a = __fadd_rn(a, fabsf(v));
        }
        S[l] = __fadd_rn(__fadd_rn(__fadd_rn(t[0], t[1]), __fadd_rn(t[2], t[3])),
                         __fadd_rn(__fadd_rn(t[4], t[5]), __fadd_rn(t[6], t[7])));
    }
    float u[8];
#pragma unroll
    for (int i = 0; i < 8; ++i) u[i] = __fadd_rn(S[i], S[i + 8]);
    float v4[4];
#pragma unroll
    for (int i = 0; i < 4; ++i) v4[i] = __fadd_rn(u[i], u[i + 4]);
    *aacc = a;
    return __fadd_rn(__fadd_rn(v4[0], v4[2]), __fadd_rn(v4[1], v4[3]));
}

// blocks 0..127: per-point z2 (np order) + fused abs-sum -> eps (single z pass).
// blocks 128..131: e2/e2h + XOR-swizzled kt-tile bf16 image of emb for linear global_load_lds:
//   tile kt (0..31) = 16KB covering k in [kt*32,+32), ALL 256 d.
//   within tile, byte (r*512 + c16*16), r=k&31, c16=0..31, holds bf16
//   emb[kt*32+r][dslot*8 .. +7] with dslot = c16 ^ (r&7)   (bank swizzle baked in).
__global__ __launch_bounds__(256) void setup_kernel(
    const float* __restrict__ z, const float* __restrict__ emb,
    float* __restrict__ z2, float* __restrict__ eps,
    float* __restrict__ e2, float* __restrict__ e2h,
    ushort_t* __restrict__ ebf,
    double* __restrict__ loss_acc, unsigned int* __restrict__ ticket)
{
    if (blockIdx.x < 128) {
        int n = blockIdx.x * 256 + threadIdx.x;
        const float* p = z + z_base(n);
        float a = 0.0f;
        float h0 = np_half_sq_abs(p, 1024, &a);
        float h1 = np_half_sq_abs(p + 128 * 1024, 1024, &a);
        z2[n] = __fadd_rn(h0, h1);
        eps[n] = __builtin_fmaf(1e-5f, a, 3e-4f);   // sound |d~ - d| bound
        if (blockIdx.x == 0 && threadIdx.x == 0) { *loss_acc = 0.0; *ticket = 0u; }
    } else {
        int kb = (blockIdx.x - 128) * 256;
        for (int i = threadIdx.x; i < 8192; i += 256) {
            int klocal = i >> 5, c16 = i & 31;
            int k = kb + klocal;
            int r = k & 31, ktc = k >> 5;
            int dslot = c16 ^ (r & 7);
            const float* e = emb + k * 256 + dslot * 8;
            short8 ov;
#pragma unroll
            for (int j = 0; j < 8; ++j) ov[j] = (short)f2bf(e[j]);
            *(short8*)(ebf + ktc * 8192 + r * 256 + c16 * 8) = ov;
        }
        int k = kb + threadIdx.x;
        float s = np_sum256_sq(emb + k * DIM, 1);
        e2[k] = s;
        e2h[k] = 0.5f * s;
    }
}

// ---------------- MFMA distance + candidate filter + exact recheck ----------------
// block: 64 pts x 1024 k; 4 waves each own 16 POINTS (mt=1), full K.
// A hoisted to 32 VGPRs. es = block-shared full-d 32-k tile (16KB), double-buffered,
// staged with linear global_load_lds; ONE __syncthreads per kt (its vmcnt0 drain is the fence).
// Running-max threshold in registers; candidates inline; no kt0 redo; no cross-wave reduction.
#define ZS_STRIDE 264

__device__ __forceinline__ void async_cp16(const ushort_t* g, ushort_t* l) {
    __builtin_amdgcn_global_load_lds(
        (const __attribute__((address_space(1))) u32*)g,
        (__attribute__((address_space(3))) u32*)l, 16, 0, 0);
}

__global__ __launch_bounds__(256, 3) void dist_kernel(
    const float* __restrict__ z, const float* __restrict__ emb,
    const ushort_t* __restrict__ ebf,
    const float* __restrict__ z2w, const float* __restrict__ e2w,
    const float* __restrict__ e2hw, const float* __restrict__ epsw,
    float* __restrict__ out_idx)
{
    // uni: zs [64][264] bf16 transient (33792B)  UNION  es 2 x 16KB (32768B)  UNION  zx 32x68 f32
    __shared__ __align__(16) short uni[16896];
    __shared__ __align__(16) int cl[2048];
    __shared__ float e2hS[1024];
    __shared__ float epsS[64], z2S[64];
    __shared__ unsigned int cntS[64];
    __shared__ unsigned long long bestS[64];
    __shared__ int ovfS;

    const int tid = threadIdx.x;
    const int w  = tid >> 6;       // wave 0..3
    const int l  = tid & 63;
    const int lq = l >> 4;
    const int lr = l & 15;
    const int n0 = blockIdx.x << 6;
    const int zb = z_base(n0);
    const int pbase = w << 4;      // wave's 16-point base

    if (tid < 64) {
        cntS[tid] = 0u; bestS[tid] = 0x7FFFFFFFFFFFFFFFULL;
        epsS[tid] = epsw[n0 + tid]; z2S[tid] = z2w[n0 + tid];
    }
    if (tid == 0) ovfS = 0;
    for (int i = tid; i < 1024; i += 256) e2hS[i] = e2hw[i];

    // stage zs (fp32 -> bf16, transpose to [pt][d]); transient
    {
        short* zs = uni;
        int q = tid & 15, d0 = tid >> 4;
#pragma unroll 4
        for (int i = 0; i < 16; ++i) {
            int d = d0 + 16 * i;
            float4 v = *(const float4*)(z + zb + (d << 10) + 4 * q);
            zs[(4 * q + 0) * ZS_STRIDE + d] = (short)f2bf(v.x);
            zs[(4 * q + 1) * ZS_STRIDE + d] = (short)f2bf(v.y);
            zs[(4 * q + 2) * ZS_STRIDE + d] = (short)f2bf(v.z);
            zs[(4 * q + 3) * ZS_STRIDE + d] = (short)f2bf(v.w);
        }
    }
    __syncthreads();

    // hoist A-fragments: wave w's 16 points, 8 d-chunks -> 32 VGPRs
    short8 af[8];
#pragma unroll
    for (int d8 = 0; d8 < 8; ++d8)
        af[d8] = *(const short8*)(uni + (pbase + lr) * ZS_STRIDE + d8 * 32 + lq * 8);

    // per-lane filter state for the 4 points (lq*4+r) this lane owns in the C layout
    float eps_r[4], Mr[4];
#pragma unroll
    for (int r = 0; r < 4; ++r) {
        eps_r[r] = epsS[pbase + lq * 4 + r];
        Mr[r] = -3.4e38f;
    }
    __syncthreads();   // all af reads done; zs region now reusable as es

    // prologue: stage kt0 into buf0 (wave w copies bytes [w*4KB, +4KB) linearly)
    {
        const ushort_t* gs = ebf + w * 2048 + (l << 3);
        ushort_t* ld = (ushort_t*)uni + w * 2048;
        async_cp16(gs,        ld);
        async_cp16(gs +  512, ld +  512);
        async_cp16(gs + 1024, ld + 1024);
        async_cp16(gs + 1536, ld + 1536);
    }

    f32x4 acc[2];
#pragma unroll
    for (int nt = 0; nt < 2; ++nt) {
        float e = e2hS[16 * nt + lr];
        f32x4 iv = { -e, -e, -e, -e };
        acc[nt] = iv;
    }
    __syncthreads();   // drains vmcnt -> kt0 tile ready for all waves

    const int c16base = (lq << 3) ^ ((lr & 7) << 3);   // (lq ^ (r&7))*8 shorts; dt adds (dt*4)^... below

#pragma unroll 1
    for (int kt = 0; kt < 32; ++kt) {
        if (kt < 31) {   // stage kt+1 into the other buffer (reads of that buffer ended at last barrier)
            const ushort_t* gs = ebf + (kt + 1) * 8192 + w * 2048 + (l << 3);
            ushort_t* ld = (ushort_t*)uni + (((kt + 1) & 1) << 13) + w * 2048;
            async_cp16(gs,        ld);
            async_cp16(gs +  512, ld +  512);
            async_cp16(gs + 1024, ld + 1024);
            async_cp16(gs + 1536, ld + 1536);
        }
        const short* esb = uni + ((kt & 1) << 13);
#pragma unroll
        for (int dt = 0; dt < 8; ++dt) {
            // c16 = (dt*4 + lq) ^ (r&7); (r&7) == (lr&7) for both nt rows
            const int c16s = (((dt << 2) + lq) ^ (lr & 7)) << 3;   // short offset
            short8 b0 = *(const short8*)(esb + (lr)      * 256 + c16s);
            short8 b1 = *(const short8*)(esb + (16 + lr) * 256 + c16s);
            acc[0] = __builtin_amdgcn_mfma_f32_16x16x32_bf16(af[dt], b0, acc[0], 0, 0, 0);
            acc[1] = __builtin_amdgcn_mfma_f32_16x16x32_bf16(af[dt], b1, acc[1], 0, 0, 0);
        }
        // ---- filter: per-point running max + candidate record (register-only, no barriers) ----
        {
            float mx[4];
#pragma unroll
            for (int r = 0; r < 4; ++r) mx[r] = fmaxf(acc[0][r], acc[1][r]);
#pragma unroll
            for (int s = 1; s <= 8; s <<= 1)
#pragma unroll
                for (int r = 0; r < 4; ++r)
                    mx[r] = fmaxf(mx[r], __shfl_xor(mx[r], s, 64));   // reduce over lr (same lq)
            float thr[4];
#pragma unroll
            for (int r = 0; r < 4; ++r) {
                Mr[r] = fmaxf(Mr[r], mx[r]);
                thr[r] = Mr[r] - eps_r[r];   // sound: any k with val >= finalMax-eps passes here too
            }
#pragma unroll
            for (int nt = 0; nt < 2; ++nt)
#pragma unroll
                for (int r = 0; r < 4; ++r) {
                    if (acc[nt][r] >= thr[r]) {
                        int p = pbase + lq * 4 + r;
                        int kk = kt * 32 + 16 * nt + lr;
                        unsigned int pos = atomicAdd(&cntS[p], 1u);
                        if (pos < 32u) cl[p * 32 + pos] = kk;
                        else atomicMax(&ovfS, 1);
                    }
                }
        }
        if (kt < 31) {   // re-init acc = -e2/2 for next tile
#pragma unroll
            for (int nt = 0; nt < 2; ++nt) {
                float e = e2hS[(kt + 1) * 32 + 16 * nt + lr];
                f32x4 iv = { -e, -e, -e, -e };
                acc[nt] = iv;
            }
        }
        __syncthreads();   // drains vmcnt (kt+1 landed for ALL waves) + WAR safety for buffers
    }

    // ---------------- exact recheck (bit-identical fp32 chain) ----------------
    float* zx = (float*)uni;                 // [32 dd][68] fp32 chunk; zs/es are dead
    const int pt = tid & 63;
    const int s0 = tid >> 6;                 // 4 slot-threads per point
    unsigned int nc = cntS[pt]; if (nc > 32u) nc = 32u;
    bool  act[8]; int kE[8]; float accE[8];
#pragma unroll
    for (int j = 0; j < 8; ++j) {
        unsigned int s = (unsigned int)s0 + 4u * j;
        act[j] = s < nc;
        kE[j] = act[j] ? cl[pt * 32 + s] : 0;
        accE[j] = 0.0f;
    }
#pragma unroll 1
    for (int dt = 0; dt < 8; ++dt) {
        const int dbase = dt * 32;
        __syncthreads();
        {
            int q = tid & 15, dd0 = tid >> 4;
            float4 v0 = *(const float4*)(z + zb + ((dbase + dd0) << 10) + 4 * q);
            float4 v1 = *(const float4*)(z + zb + ((dbase + dd0 + 16) << 10) + 4 * q);
            *(float4*)(zx + dd0 * 68 + 4 * q) = v0;
            *(float4*)(zx + (dd0 + 16) * 68 + 4 * q) = v1;
        }
        __syncthreads();
#pragma unroll
        for (int j = 0; j < 8; ++j) {
            if (!act[j]) continue;
            const float* er = emb + kE[j] * 256 + dbase;
            float ev[32];
#pragma unroll
            for (int c = 0; c < 8; ++c) *(float4*)(ev + 4 * c) = *(const float4*)(er + 4 * c);
            float a = accE[j];
#pragma unroll
            for (int dd = 0; dd < 32; ++dd)
                a = __builtin_fmaf(zx[dd * 68 + pt], ev[dd], a);
            accE[j] = a;
        }
    }
#pragma unroll
    for (int j = 0; j < 8; ++j) {
        if (!act[j]) continue;
        int k = kE[j];
        float t1 = __fadd_rn(z2S[pt], e2w[k]);
        float d  = __fsub_rn(t1, __fmul_rn(2.0f, accE[j]));
        atomicMin(&bestS[pt], pack_vi(d, k));
    }
    __syncthreads();

    if (ovfS) {   // near-impossible fallback: full exact scan for overflowed points
        for (int row = 0; row < 64; ++row) {
            if (cntS[row] <= 32u) continue;
            float fa[4] = {0.f, 0.f, 0.f, 0.f};
            for (int dt = 0; dt < 8; ++dt) {
                const int dbase = dt * 32;
                __syncthreads();
                {
                    int q = tid & 15, dd0 = tid >> 4;
                    float4 v0 = *(const float4*)(z + zb + ((dbase + dd0) << 10) + 4 * q);
                    float4 v1 = *(const float4*)(z + zb + ((dbase + dd0 + 16) << 10) + 4 * q);
                    *(float4*)(zx + dd0 * 68 + 4 * q) = v0;
                    *(float4*)(zx + (dd0 + 16) * 68 + 4 * q) = v1;
                }
                __syncthreads();
                for (int c = 0; c < 4; ++c) {
                    const float* er = emb + (tid + 256 * c) * 256 + dbase;
                    for (int dd = 0; dd < 32; ++dd)
                        fa[c] = __builtin_fmaf(zx[dd * 68 + row], er[dd], fa[c]);
                }
            }
            for (int c = 0; c < 4; ++c) {
                int k = tid + 256 * c;
                float t1 = __fadd_rn(z2S[row], e2w[k]);
                float d  = __fsub_rn(t1, __fmul_rn(2.0f, fa[c]));
                atomicMin(&bestS[row], pack_vi(d, k));
            }
            __syncthreads();
        }
    }

    if (tid < 64)
        out_idx[n0 + tid] = (float)(unsigned int)(bestS[tid] & 0xFFFFFFFFULL);
}

// 256 blocks: each block 128 points, d split in halves across the two thread-halves.
__global__ __launch_bounds__(256) void zq_loss_kernel(
    const float* __restrict__ z, const float* __restrict__ emb,
    const float* __restrict__ idxv, float* __restrict__ zq,
    double* __restrict__ loss_acc, unsigned int* __restrict__ ticket,
    float* __restrict__ out_loss)
{
    const int tl = threadIdx.x & 127;
    const int h  = threadIdx.x >> 7;         // d-half
    const int n  = blockIdx.x * 128 + tl;
    const int kk = (int)idxv[n];
    const float* er = emb + kk * DIM + (h << 7);
    const int zb2 = z_base(n) + (h << 17);   // + (h*128)<<10
    double s = 0.0;
#pragma unroll 8
    for (int dd = 0; dd < 128; ++dd) {
        float ev = er[dd];
        float zv = z[zb2 + (dd << 10)];
        zq[zb2 + (dd << 10)] = ev;
        float df = ev - zv;
        s = fma((double)df, (double)df, s);
    }
    for (int off = 32; off; off >>= 1) s += __shfl_down(s, off, 64);
    __shared__ double sred[4];
    if ((threadIdx.x & 63) == 0) sred[threadIdx.x >> 6] = s;
    __syncthreads();
    if (threadIdx.x == 0) {
        atomicAdd(loss_acc, (sred[0] + sred[1]) + (sred[2] + sred[3]));
        __threadfence();
        unsigned int old = atomicAdd(ticket, 1u);
        if (old == gridDim.x - 1) {
            double total = atomicAdd(loss_acc, 0.0);
            out_loss[0] = (float)(1.25 * (total / 8388608.0));
        }
    }
}

extern "C" void kernel_launch(void* const* d_in, const int* in_sizes, int n_in,
                              void* d_out, int out_size, void* d_ws, size_t ws_size,
                              hipStream_t stream) {
    const float* z   = (const float*)d_in[0];
    const float* emb = (const float*)d_in[1];
    float* out = (float*)d_out;

    // ws: z2[32768]f32 @0 | eps[32768]f32 @131072 | e2[1024] @262144 |
    //     e2h[1024] @266240 | ebf16(kt-tiled image) @270336 | loss f64 @794624 | ticket @794632
    float* z2w = (float*)d_ws;
    float* epsw = (float*)((char*)d_ws + 131072);
    float* e2w = (float*)((char*)d_ws + 262144);
    float* e2hw = (float*)((char*)d_ws + 266240);
    ushort_t* ebf = (ushort_t*)((char*)d_ws + 270336);
    double* loss_acc = (double*)((char*)d_ws + 794624);
    unsigned int* ticket = (unsigned int*)((char*)d_ws + 794632);

    setup_kernel<<<132, 256, 0, stream>>>(z, emb, z2w, epsw, e2w, e2hw, ebf,
                                          loss_acc, ticket);
    dist_kernel<<<NPTS / 64, 256, 0, stream>>>(z, emb, ebf, z2w, e2w, e2hw, epsw,
                                               out + IDX_OFF);
    zq_loss_kernel<<<256, 256, 0, stream>>>(z, emb, out + IDX_OFF,
                                            out + ZQ_OFF, loss_acc, ticket,
                                            out + LOSS_OFF);
}